// Round 1
// 133.243 us; speedup vs baseline: 1.0340x; 1.0340x over previous
//
#include <hip/hip_runtime.h>
#include <stdint.h>

#define B_ 4
#define T_ 2048
#define C_ 1024
#define H_ 128
#define NEG_BIG -3.0e38f

typedef __attribute__((ext_vector_type(8))) short short8;
typedef __attribute__((ext_vector_type(4))) float f32x4;
typedef __attribute__((ext_vector_type(4))) unsigned short ushort4v;
typedef __attribute__((ext_vector_type(8))) unsigned short ushort8v;

// cheap bf16 cast: round-half-up, <=0.5 ULP (validated R6-R9: absmax unchanged)
__device__ __forceinline__ unsigned short f2bf(float f) {
  union { float f; unsigned u; } cv; cv.f = f;
  return (unsigned short)((cv.u + 0x8000u) >> 16);
}

__device__ __forceinline__ float bf2f(unsigned short s) {
  union { unsigned u; float f; } cv; cv.u = ((unsigned)s) << 16;
  return cv.f;
}

// async global->LDS, 16 bytes per lane. LDS dest = wave-uniform base + lane*16.
__device__ __forceinline__ void gld16(const void* g, void* l) {
  __builtin_amdgcn_global_load_lds(
      (const __attribute__((address_space(1))) unsigned int*)g,
      (__attribute__((address_space(3))) unsigned int*)l, 16, 0, 0);
}

// scale = C^-0.5 = 1/32; folded with log2(e) for exp2-domain softmax
#define CSCALE 0.045084220027780106f

// ---------------------------------------------------------------------------
// Kernel 1: prep_w — cast Wq|Wk|Wv (fp32 [1024][128]) to WbT bf16 [384][1024]
// (transposed so B-fragments are contiguous). Tiny: ~2.3 MB traffic.
// ---------------------------------------------------------------------------
__global__ __launch_bounds__(256) void prep_w(const float* __restrict__ Wq,
                                              const float* __restrict__ Wk,
                                              const float* __restrict__ Wv,
                                              unsigned short* __restrict__ WbT) {
  const int i = blockIdx.x * 256 + threadIdx.x;   // 0..98303
  const int linear = i * 4;
  const int j = linear >> 10;
  const int k0 = linear & 1023;
  const float* W = (j < 128) ? Wq : (j < 256) ? Wk : Wv;
  const int h = j & 127;
  ushort4v p;
  p[0] = f2bf(W[(k0 + 0) * 128 + h]);
  p[1] = f2bf(W[(k0 + 1) * 128 + h]);
  p[2] = f2bf(W[(k0 + 2) * 128 + h]);
  p[3] = f2bf(W[(k0 + 3) * 128 + h]);
  *(ushort4v*)(WbT + linear) = p;
}

// ---------------------------------------------------------------------------
// Kernel 2: fused x-cast + QKV projection.
// R10: 64M x 96N x 64K tiles, grid = 128 rb x 4 cb = 512 blocks -> 2 blocks/CU
// (was 1: zero TLP, every load latency + barrier drain exposed).
// Decode rb = bid&127, cb = bid>>7: the 4 cb-siblings sharing rb's x rows are
// bids {rb, rb+128, rb+256, rb+384} == rb (mod 8) -> SAME XCD, co-resident ->
// x fetched once per XCD (was 4x via round-robin XCD spread).
// LDS 40 KB dbuf. Waves 2x2: wave owns 32M x 48N (2 mt x 3 nt) -> 12 MFMA +
// 10 ds_read_b128 per iter.
// ---------------------------------------------------------------------------
__global__ __launch_bounds__(256, 2) void qkv_proj(const float* __restrict__ x,
                                                   const unsigned short* __restrict__ WbT,
                                                   unsigned short* __restrict__ Qb,
                                                   unsigned short* __restrict__ Kb,
                                                   unsigned short* __restrict__ VT) {
  __shared__ unsigned short As[2][64 * 64];   // 8 KB each
  __shared__ unsigned short Bs[2][96 * 64];   // 12 KB each

  const int tid  = threadIdx.x;
  const int wave = tid >> 6, lane = tid & 63;
  const int quad = lane >> 4, l15 = lane & 15;
  const int rb = blockIdx.x & 127, cb = blockIdx.x >> 7;  // siblings same XCD
  const int gm0 = rb * 64, gn0 = cb * 96;
  const int wm = wave >> 1, wn = wave & 1;

  const int srow = lane >> 3, sslot = lane & 7;   // B staging: 8 rows x 8 slots
  // A staging: thread -> (row = tid>>3 (+32q), chunk = tid&7)
  const int axr = tid >> 3, axc = tid & 7;        // 32 rows x 8 chunks
  const float* gAx = x + (size_t)(gm0 + axr) * C_ + axc * 8;

  // fragment read offsets (shorts)
  int aoff[2][2], boff[3][2];
#pragma unroll
  for (int mt = 0; mt < 2; ++mt) {
    const int r = wm * 32 + mt * 16 + l15;
#pragma unroll
    for (int ks = 0; ks < 2; ++ks)
      aoff[mt][ks] = r * 64 + (((ks * 4 + quad) ^ r) & 7) * 8;
  }
#pragma unroll
  for (int nt = 0; nt < 3; ++nt) {
    const int r = wn * 48 + nt * 16 + l15;
#pragma unroll
    for (int ks = 0; ks < 2; ++ks)
      boff[nt][ks] = r * 64 + (((ks * 4 + quad) ^ r) & 7) * 8;
  }

  f32x4 acc[2][3];
  const f32x4 zero4 = {0.f, 0.f, 0.f, 0.f};
#pragma unroll
  for (int mt = 0; mt < 2; ++mt)
#pragma unroll
    for (int nt = 0; nt < 3; ++nt) acc[mt][nt] = zero4;

  // B staging via async gld16
#define STAGE_B(buf, kb_)                                                          \
  {                                                                                \
    const int ko = (kb_) * 64;                                                     \
    _Pragma("unroll")                                                              \
    for (int q = 0; q < 3; ++q) {                                                  \
      const int row = wave * 24 + q * 8 + srow;                                    \
      gld16(WbT + (size_t)(gn0 + row) * C_ + ko + ((sslot ^ row) & 7) * 8,         \
            &Bs[buf][(wave * 24 + q * 8) * 64]);                                   \
    }                                                                              \
  }

  // A: load fp32 tile (q=0..1 -> rows axr+32q), 2 f32x4 per q
#define LOAD_A(ko_)                                                                \
  _Pragma("unroll")                                                                \
  for (int q = 0; q < 2; ++q) {                                                    \
    av0[q] = *(const f32x4*)(gAx + (size_t)(q * 32) * C_ + (ko_));                 \
    av1[q] = *(const f32x4*)(gAx + (size_t)(q * 32) * C_ + (ko_) + 4);             \
  }

  // A: cvt + swizzled ds_write_b128 into buffer buf
#define WRITE_A(buf)                                                               \
  _Pragma("unroll")                                                                \
  for (int q = 0; q < 2; ++q) {                                                    \
    const int row = axr + q * 32;                                                  \
    short8 aw;                                                                     \
    _Pragma("unroll")                                                              \
    for (int e = 0; e < 4; ++e) {                                                  \
      aw[e]     = (short)f2bf(av0[q][e]);                                          \
      aw[4 + e] = (short)f2bf(av1[q][e]);                                          \
    }                                                                              \
    *(short8*)(&As[buf][row * 64 + ((axc ^ row) & 7) * 8]) = aw;                   \
  }

  f32x4 av0[2], av1[2];
  // preload tile 0
  LOAD_A(0);
  STAGE_B(0, 0);
  WRITE_A(0);

  for (int kb = 0; kb < 16; ++kb) {
    __syncthreads();               // buf[kb&1] staged; prior reads of other done
    const int cur = kb & 1, nxt = cur ^ 1;
    if (kb + 1 < 16) {             // issue next-tile loads right after barrier
      LOAD_A((kb + 1) * 64);
      STAGE_B(nxt, kb + 1);
    }
    const unsigned short* Ac = As[cur];
    const unsigned short* Bc = Bs[cur];
#pragma unroll
    for (int ks = 0; ks < 2; ++ks) {
      short8 b0 = *(const short8*)(Bc + boff[0][ks]);
      short8 b1 = *(const short8*)(Bc + boff[1][ks]);
      short8 b2 = *(const short8*)(Bc + boff[2][ks]);
#pragma unroll
      for (int mt = 0; mt < 2; ++mt) {
        short8 a = *(const short8*)(Ac + aoff[mt][ks]);
        acc[mt][0] = __builtin_amdgcn_mfma_f32_16x16x32_bf16(a, b0, acc[mt][0], 0, 0, 0);
        acc[mt][1] = __builtin_amdgcn_mfma_f32_16x16x32_bf16(a, b1, acc[mt][1], 0, 0, 0);
        acc[mt][2] = __builtin_amdgcn_mfma_f32_16x16x32_bf16(a, b2, acc[mt][2], 0, 0, 0);
      }
    }
    if (kb + 1 < 16) WRITE_A(nxt);  // cvt + write next A after MFMAs issued
  }
#undef STAGE_B
#undef LOAD_A
#undef WRITE_A

  // epilogue: D[row=quad*4+r][col=l15] per 16x16 tile
#pragma unroll
  for (int mt = 0; mt < 2; ++mt) {
    const int row0 = gm0 + wm * 32 + mt * 16 + quad * 4;
#pragma unroll
    for (int nt = 0; nt < 3; ++nt) {
      const int colbase = gn0 + wn * 48 + nt * 16;
      const int col = colbase + l15;
      if (colbase < 128) {          // Q (pre-scaled)
#pragma unroll
        for (int r = 0; r < 4; ++r)
          Qb[(size_t)(row0 + r) * H_ + col] = f2bf(acc[mt][nt][r] * CSCALE);
      } else if (colbase < 256) {   // K
#pragma unroll
        for (int r = 0; r < 4; ++r)
          Kb[(size_t)(row0 + r) * H_ + (col - 128)] = f2bf(acc[mt][nt][r]);
      } else {                      // V, transposed
        const int h = col - 256;
        const int bidx = row0 >> 11;
        const int t0 = row0 & 2047;
        ushort4v pk;
        pk[0] = f2bf(acc[mt][nt][0]); pk[1] = f2bf(acc[mt][nt][1]);
        pk[2] = f2bf(acc[mt][nt][2]); pk[3] = f2bf(acc[mt][nt][3]);
        *(ushort4v*)(VT + (size_t)(bidx * H_ + h) * T_ + t0) = pk;
      }
    }
  }
}

// ---------------------------------------------------------------------------
// Kernel 3: flash attention stage 1 (R9 compute, R10 schedule).
// Load-balanced causal pairing: block (b, jp, ch) processes q-row-blocks
// j1 = jp AND j2 = 31-jp (sequentially, reusing regs), each with the strided
// tile set { t : t == ch (mod 8), t <= j }. Row pair totals 33 tiles over 8
// chunks -> EVERY block gets 4-5 tiles (was 0-8, worst CU 16 tiles, 192 idle
// blocks). Grid 512 @ 2/CU, all slots busy. Online softmax is order-
// independent, so strided tiles are numerically identical to contiguous.
// All chunks write partials; attn2 combines every row (nch = min(j+1,8)).
// ---------------------------------------------------------------------------
__global__ __launch_bounds__(256, 2) void attn1(const unsigned short* __restrict__ Qb,
                                                const unsigned short* __restrict__ Kb,
                                                const unsigned short* __restrict__ VT,
                                                unsigned short* __restrict__ Opart,
                                                float* __restrict__ mpart,
                                                float* __restrict__ lpart) {
  __shared__ unsigned short Ks[2][64 * 128];   // 16 KB each; 16-slot rows
  __shared__ unsigned short Vs[2][128 * 64];   // 16 KB each; 8-slot rows
  __shared__ unsigned short Pls[4][16 * 72];   // 9 KB, per-wave P, pad 72
  __shared__ float Als[4][16];

  const int bid = blockIdx.x;
  const int b  = bid & 3;          // bid%8 fixes b per XCD -> per-XCD KV locality
  const int jp = (bid >> 2) & 15;
  const int ch = bid >> 6;         // 0..7
  const int j1 = jp, j2 = 31 - jp;
  const int n1 = (ch <= j1) ? (((j1 - ch) >> 3) + 1) : 0;  // tiles for row j1
  const int n2 = ((j2 - ch) >> 3) + 1;                     // tiles for row j2 (>=2)
  const int ntt = n1 + n2;                                 // 4..5 always

  const int tid  = threadIdx.x;
  const int wave = tid >> 6, lane = tid & 63;
  const int quad = lane >> 4, l15 = lane & 15;

  const unsigned short* Kb_b = Kb + (size_t)(b * T_) * H_;
  const unsigned short* VT_b = VT + (size_t)(b * H_) * T_;

  const int k_row4 = lane >> 4, k_slot = lane & 15;
  const int v_row8 = lane >> 3, v_slot = lane & 7;

#define STAGE_KV(buf, kv0_)                                                        \
  {                                                                                \
    _Pragma("unroll")                                                              \
    for (int i_ = 0; i_ < 4; ++i_) {                                               \
      const int r = wave * 16 + i_ * 4 + k_row4;                                   \
      const int c2 = (k_slot & 8) | ((k_slot ^ r) & 7);                            \
      gld16(Kb_b + (size_t)((kv0_) + r) * H_ + c2 * 8,                             \
            &Ks[buf][(wave * 16 + i_ * 4) * 128]);                                 \
    }                                                                              \
    _Pragma("unroll")                                                              \
    for (int i_ = 0; i_ < 4; ++i_) {                                               \
      const int h = wave * 32 + i_ * 8 + v_row8;                                   \
      gld16(VT_b + (size_t)h * T_ + (kv0_) + ((v_slot ^ h) & 7) * 8,               \
            &Vs[buf][(wave * 32 + i_ * 8) * 64]);                                  \
    }                                                                              \
  }

  // partial epilogue: un-normalized O (bf16) + m, l for row jr_
#define EPI(jr_)                                                                   \
  {                                                                                \
    const int pid = (b * 32 + (jr_)) * 8 + ch;                                     \
    unsigned short* po = Opart + (size_t)(pid * 64 + wave * 16) * H_;              \
    _Pragma("unroll")                                                              \
    for (int nth = 0; nth < 8; ++nth)                                              \
      _Pragma("unroll")                                                            \
      for (int r = 0; r < 4; ++r)                                                  \
        po[(quad * 4 + r) * H_ + nth * 16 + l15] = f2bf(O[nth][r]);                \
    if (lane < 16) {                                                               \
      mpart[pid * 64 + wave * 16 + lane] = m_;                                     \
      lpart[pid * 64 + wave * 16 + lane] = l_;                                     \
    }                                                                              \
  }

  // Q fragments for current row block
  int jr_cur = n1 ? j1 : j2;
  short8 aq[4];
  {
    const unsigned short* qrow = Qb + (size_t)(b * T_ + jr_cur * 64 + wave * 16 + l15) * H_;
#pragma unroll
    for (int ks = 0; ks < 4; ++ks)
      aq[ks] = *(const short8*)(qrow + ks * 32 + quad * 8);
  }

  STAGE_KV(0, ch * 64);   // tile 0 is always absolute tile index ch

  const f32x4 zero4 = {0.f, 0.f, 0.f, 0.f};
  f32x4 O[8];
#pragma unroll
  for (int nth = 0; nth < 8; ++nth) O[nth] = zero4;
  float m_ = NEG_BIG, l_ = 0.f;

  for (int i = 0; i < ntt; ++i) {
    __syncthreads();
    if (i + 1 < ntt) {
      const int in_ = i + 1;
      const int tn = (in_ < n1) ? (ch + (in_ << 3)) : (ch + ((in_ - n1) << 3));
      STAGE_KV((in_) & 1, tn * 64);
    }
    if (n1 && i == n1) {
      // finalize row j1, reset state, switch Q to row j2
      EPI(j1);
      m_ = NEG_BIG; l_ = 0.f;
#pragma unroll
      for (int nth = 0; nth < 8; ++nth) O[nth] = zero4;
      jr_cur = j2;
      const unsigned short* qrow = Qb + (size_t)(b * T_ + j2 * 64 + wave * 16 + l15) * H_;
#pragma unroll
      for (int ks = 0; ks < 4; ++ks)
        aq[ks] = *(const short8*)(qrow + ks * 32 + quad * 8);
    }
    const int ti  = (i < n1) ? (ch + (i << 3)) : (ch + ((i - n1) << 3));
    const int kv0 = ti * 64;

    // ---- S^T = K . Q^T
    const unsigned short* kb = Ks[i & 1];
    f32x4 ST[4];
    ST[0] = zero4; ST[1] = zero4; ST[2] = zero4; ST[3] = zero4;
#pragma unroll
    for (int ntl = 0; ntl < 4; ++ntl) {
      const int kvr = ntl * 16 + l15;
#pragma unroll
      for (int ks = 0; ks < 4; ++ks) {
        const int c = ks * 4 + quad;
        const int slot = (c & 8) | ((c ^ kvr) & 7);
        short8 kf = *(const short8*)(kb + kvr * 128 + slot * 8);
        ST[ntl] = __builtin_amdgcn_mfma_f32_16x16x32_bf16(kf, aq[ks], ST[ntl], 0, 0, 0);
      }
    }

    // ---- causal mask (diagonal tile only)
    if (ti == jr_cur) {
      const int ql = jr_cur * 64 + wave * 16 + l15;
#pragma unroll
      for (int ntl = 0; ntl < 4; ++ntl)
#pragma unroll
        for (int r = 0; r < 4; ++r) {
          const int kl = kv0 + ntl * 16 + quad * 4 + r;
          if (kl > ql) ST[ntl][r] = NEG_BIG;
        }
    }

    // ---- softmax (per lane q=l15)
    float vmax = ST[0][0];
#pragma unroll
    for (int ntl = 0; ntl < 4; ++ntl)
#pragma unroll
      for (int r = 0; r < 4; ++r) vmax = fmaxf(vmax, ST[ntl][r]);
    vmax = fmaxf(vmax, __shfl_xor(vmax, 16));
    vmax = fmaxf(vmax, __shfl_xor(vmax, 32));
    const float mn = fmaxf(m_, vmax);
    const float alpha = __builtin_amdgcn_exp2f(m_ - mn);
    m_ = mn;
    float s = 0.f;
#pragma unroll
    for (int ntl = 0; ntl < 4; ++ntl)
#pragma unroll
      for (int r = 0; r < 4; ++r) {
        const float p = __builtin_amdgcn_exp2f(ST[ntl][r] - mn);
        ST[ntl][r] = p;
        s += p;
      }
    s += __shfl_xor(s, 16);
    s += __shfl_xor(s, 32);
    l_ = l_ * alpha + s;

    // ---- P -> LDS ([q][kv] layout)
#pragma unroll
    for (int ntl = 0; ntl < 4; ++ntl) {
      ushort4v pk;
      pk[0] = f2bf(ST[ntl][0]); pk[1] = f2bf(ST[ntl][1]);
      pk[2] = f2bf(ST[ntl][2]); pk[3] = f2bf(ST[ntl][3]);
      *(ushort4v*)(&Pls[wave][l15 * 72 + ntl * 16 + quad * 4]) = pk;
    }

    // ---- O rescale by alpha
    if (lane < 16) Als[wave][lane] = alpha;
    if (!__all(alpha == 1.f)) {
      f32x4 al4 = *(const f32x4*)&Als[wave][quad * 4];
#pragma unroll
      for (int nth = 0; nth < 8; ++nth)
#pragma unroll
        for (int r = 0; r < 4; ++r) O[nth][r] *= al4[r];
    }

    // ---- O += P . V
    const unsigned short* vb = Vs[i & 1];
    short8 ap0 = *(const short8*)(&Pls[wave][l15 * 72 + quad * 8]);
    short8 ap1 = *(const short8*)(&Pls[wave][l15 * 72 + 32 + quad * 8]);
#pragma unroll
    for (int nth = 0; nth < 8; ++nth) {
      const int h = nth * 16 + l15;
      short8 v0 = *(const short8*)(vb + h * 64 + ((quad ^ h) & 7) * 8);
      short8 v1 = *(const short8*)(vb + h * 64 + (((4 + quad) ^ h) & 7) * 8);
      O[nth] = __builtin_amdgcn_mfma_f32_16x16x32_bf16(ap0, v0, O[nth], 0, 0, 0);
      O[nth] = __builtin_amdgcn_mfma_f32_16x16x32_bf16(ap1, v1, O[nth], 0, 0, 0);
    }
  }
  EPI(j2);
#undef STAGE_KV
#undef EPI
}

// ---------------------------------------------------------------------------
// Kernel 4: stage-2 combine, now for ALL rows. Grid = 4 b x 32 j = 128 blocks.
// Row j has contributors ch in [0, min(j+1,8)).
// ---------------------------------------------------------------------------
__global__ __launch_bounds__(256) void attn2(const unsigned short* __restrict__ Opart,
                                             const float* __restrict__ mpart,
                                             const float* __restrict__ lpart,
                                             float* __restrict__ out) {
  const int b = blockIdx.x & 3;
  const int j = blockIdx.x >> 2;      // 0..31
  const int nch = min(j + 1, 8);      // 1..8
  const int tid = threadIdx.x;
  const int qh = tid >> 4;            // 0..15
  const int h0 = (tid & 15) * 8;
  const int pbase = (b * 32 + j) * 8;

#pragma unroll
  for (int i = 0; i < 4; ++i) {
    const int q = qh + i * 16;        // 0..63
    float m_fin = NEG_BIG;
    for (int ch = 0; ch < nch; ++ch)
      m_fin = fmaxf(m_fin, mpart[(pbase + ch) * 64 + q]);
    float lf = 0.f;
    float o[8];
#pragma unroll
    for (int c = 0; c < 8; ++c) o[c] = 0.f;
    for (int ch = 0; ch < nch; ++ch) {
      const int pid = pbase + ch;
      const float sc = __builtin_amdgcn_exp2f(mpart[pid * 64 + q] - m_fin);
      lf += sc * lpart[pid * 64 + q];
      ushort8v pv = *(const ushort8v*)(Opart + (size_t)(pid * 64 + q) * H_ + h0);
#pragma unroll
      for (int c = 0; c < 8; ++c) o[c] += sc * bf2f(pv[c]);
    }
    const float inv = 1.0f / lf;
    float* op = out + (size_t)(b * T_ + j * 64 + q) * H_ + h0;
    f32x4 v0 = {o[0] * inv, o[1] * inv, o[2] * inv, o[3] * inv};
    f32x4 v1 = {o[4] * inv, o[5] * inv, o[6] * inv, o[7] * inv};
    *(f32x4*)(op) = v0;
    *(f32x4*)(op + 4) = v1;
  }
}

// ---------------------------------------------------------------------------
extern "C" void kernel_launch(void* const* d_in, const int* in_sizes, int n_in,
                              void* d_out, int out_size, void* d_ws, size_t ws_size,
                              hipStream_t stream) {
  const float* x  = (const float*)d_in[0];
  const float* Wq = (const float*)d_in[1];
  const float* Wk = (const float*)d_in[2];
  const float* Wv = (const float*)d_in[3];
  float* out = (float*)d_out;

  char* ws = (char*)d_ws;
  unsigned short* WbT = (unsigned short*)(ws);              // [0, 768 KB)
  unsigned short* Qb  = (unsigned short*)(ws + 1048576);    // [1 MB, 3 MB)
  unsigned short* Kb  = (unsigned short*)(ws + 3145728);    // [3 MB, 5 MB)
  unsigned short* VT  = (unsigned short*)(ws + 5242880);    // [5 MB, 7 MB)
  unsigned short* Opart = (unsigned short*)(ws + 8388608);  // [8 MB, 24 MB): 1024 pids x 64q x 128h bf16
  float* mpart = (float*)(ws + 25165824);                   // [24 MB, +256 KB)
  float* lpart = (float*)(ws + 25427968);                   // [24.25 MB, +256 KB)

  prep_w<<<dim3(384), dim3(256), 0, stream>>>(Wq, Wk, Wv, WbT);
  qkv_proj<<<dim3(512), dim3(256), 0, stream>>>(x, WbT, Qb, Kb, VT);
  attn1<<<dim3(512), dim3(256), 0, stream>>>(Qb, Kb, VT, Opart, mpart, lpart);
  attn2<<<dim3(128), dim3(256), 0, stream>>>(Opart, mpart, lpart, out);
}